// Round 9
// baseline (399.094 us; speedup 1.0000x reference)
//
#include <hip/hip_runtime.h>

typedef __attribute__((ext_vector_type(4))) float f32x4;
typedef __attribute__((ext_vector_type(8))) __bf16 bf16x8;

constexpr int FD = 128;   // feature dim D = H = 128

__device__ __forceinline__ uint4 pack8(const float* v) {
  union { __bf16 h[8]; uint4 u; } cv;
#pragma unroll
  for (int q = 0; q < 8; ++q) cv.h[q] = (__bf16)v[q];
  return cv.u;
}
__device__ __forceinline__ unsigned int pack2(float a, float b) {
  union { __bf16 h[2]; unsigned int u; } cv;
  cv.h[0] = (__bf16)a; cv.h[1] = (__bf16)b;
  return cv.u;
}

// node_x f32 -> bf16 table (halves random-gather bytes in the edge kernel)
__global__ void cvt_bf16(const float* __restrict__ x, unsigned short* __restrict__ o, int n8) {
  int i = blockIdx.x * 256 + threadIdx.x;
  if (i >= n8) return;
  const float* p = x + (size_t)i * 8;
  float v[8];
#pragma unroll
  for (int q = 0; q < 8; ++q) v[q] = p[q];
  *(uint4*)(o + (size_t)i * 8) = pack8(v);
}

// Pack a (K,128) f32 weight matrix into 16x16x32 MFMA B-fragment order, bf16:
// dst[((nt*KS + ks)*64 + lane)*8 + e] = W[k][n]
__global__ void pack_weights(const float* __restrict__ mw0, const float* __restrict__ mw1,
                             const float* __restrict__ mw2, const float* __restrict__ uw0,
                             const float* __restrict__ uw1, const float* __restrict__ uw2,
                             unsigned short* __restrict__ wp) {
  int tid = blockIdx.x * 256 + threadIdx.x;   // 576*256 == 147456 exactly
  const float* src; int base, K;
  if      (tid < 49152)  { src = mw0; base = 0;      K = 384; }
  else if (tid < 65536)  { src = mw1; base = 49152;  K = 128; }
  else if (tid < 81920)  { src = mw2; base = 65536;  K = 128; }
  else if (tid < 114688) { src = uw0; base = 81920;  K = 256; }
  else if (tid < 131072) { src = uw1; base = 114688; K = 128; }
  else                   { src = uw2; base = 131072; K = 128; }
  int i = tid - base;
  int k = i >> 7, n = i & 127;
  int KS = K >> 5;
  int dst = base + (((n >> 4) * KS + (k >> 5)) * 64 + ((k >> 3) & 3) * 16 + (n & 15)) * 8 + (k & 7);
  union { __bf16 h; unsigned short s; } cv; cv.h = (__bf16)src[i];
  wp[dst] = cv.s;
}

// Fragment-order LDS layout (R7, validated): chunk(ks,m,lane) at shorts offset
// ((ks*4+m)*64 + (lane&15)*4 + (lane>>4))*8, holding A[m*16+ln][ks*32+g16*8..+8].

template<bool RELU>
__device__ __forceinline__ void store_frag(unsigned short* sDst, const f32x4* acc, float bias) {
#pragma unroll
  for (int m = 0; m < 4; ++m)
#pragma unroll
    for (int ri = 0; ri < 4; ++ri) {
      float v = acc[m][ri] + bias;
      if (RELU) v = fmaxf(v, 0.f);
      union { __bf16 h; unsigned short s; } cv; cv.h = (__bf16)v;
      sDst[m * 512 + ri * 32] = cv.s;
    }
}

// Edge kernel: 128 edges/block as TWO 64-edge tiles, software-pipelined:
// tile1's random x-gathers are issued after tile0's L0 barrier (into registers)
// and written to LDS after tile0's epilogue -> gather latency hidden under compute.
__global__ __launch_bounds__(512, 6)
void in_edge_kernel(const float* __restrict__ node_x, const unsigned short* __restrict__ nxbf,
                    const float* __restrict__ edge_attr,
                    const int* __restrict__ eidx, const unsigned short* __restrict__ wp,
                    const float* __restrict__ b0p, const float* __restrict__ b1p,
                    const float* __restrict__ b2p, const float* __restrict__ gp,
                    const float* __restrict__ bep,
                    unsigned short* __restrict__ msg, int* __restrict__ head,
                    int* __restrict__ nxt, float* __restrict__ agg,
                    int use_sort, int E) {
  __shared__ unsigned short sBuf[3072 * 8];   // 48KB frag-order buffer
  __shared__ int sSrc[2][64], sDst[2][64];
  __shared__ float sG[128], sB[128];

  const int t = threadIdx.x;
  const int e00 = blockIdx.x * 128;
  const int lane = t & 63, w = t >> 6;
  const int ln = lane & 15, g16 = lane >> 4;
  const int col = w * 16 + ln;
  const int rdoff = ln * 32 + g16 * 8;
  const int stoff = (w >> 1) * 2048 + g16 * 128
                  + (((2 * w) + (ln >> 3)) & 3) * 8 + (ln & 7);

  // bx: dual-role regs — L0 4-deep B rotation, then B2r. B1r persistent.
  bf16x8 bx[4], B1r[4];
#pragma unroll
  for (int k = 0; k < 4; ++k)
    bx[k] = *(const bf16x8*)(wp + (size_t)((w * 12 + k) * 64 + lane) * 8);
#pragma unroll
  for (int k = 0; k < 4; ++k)
    B1r[k] = *(const bf16x8*)(wp + 49152 + (size_t)((w * 4 + k) * 64 + lane) * 8);

  uint4 pfv[2], pfu[2];   // x-gather prefetch registers

  auto gatherX = [&](int eb, const int (&S)[64], const int (&D)[64]) {
#pragma unroll
    for (int it = 0; it < 2; ++it) {
      int f = t + it * 512;
      int row = f >> 4, j = f & 15;
      uint4 v = {0, 0, 0, 0}, u = {0, 0, 0, 0};
      if (eb + row < E) {
        v = *(const uint4*)(nxbf + (size_t)D[row] * FD + j * 8);
        u = *(const uint4*)(nxbf + (size_t)S[row] * FD + j * 8);
      }
      pfv[it] = v; pfu[it] = u;
    }
  };
  auto writeX = [&]() {
#pragma unroll
    for (int it = 0; it < 2; ++it) {
      int f = t + it * 512;
      int row = f >> 4, j = f & 15;
      int c = (((j >> 2) * 4 + (row >> 4)) * 64 + (row & 15) * 4 + (j & 3)) * 8;
      *(uint4*)&sBuf[c] = pfv[it];
      *(uint4*)&sBuf[c + 8192] = pfu[it];
    }
  };
  auto stageXf32 = [&](int eb, const int (&S)[64], const int (&D)[64]) {
#pragma unroll
    for (int it = 0; it < 16; ++it) {
      const int type = it >> 3;
      int row = ((it & 7) << 3) + w;
      float2 v = {0.f, 0.f};
      if (eb + row < E) {
        const float* sp = (type == 0) ? node_x + (size_t)D[row] * FD
                                      : node_x + (size_t)S[row] * FD;
        v = *(const float2*)(sp + lane * 2);
      }
      int c = (((type * 4 + (lane >> 4)) * 4 + (row >> 4)) * 64
               + (row & 15) * 4 + ((lane >> 2) & 3)) * 8 + (lane & 3) * 2;
      *(unsigned int*)&sBuf[c] = pack2(v.x, v.y);
    }
  };
  auto stageEA = [&](int eb) {
#pragma unroll
    for (int it = 0; it < 8; ++it) {
      int row = it * 8 + w;
      float2 v = {0.f, 0.f};
      if (eb + row < E) v = *(const float2*)(edge_attr + (size_t)(eb + row) * FD + lane * 2);
      int c = 16384 + (((lane >> 4) * 4 + (row >> 4)) * 64
                       + (row & 15) * 4 + ((lane >> 2) & 3)) * 8 + (lane & 3) * 2;
      *(unsigned int*)&sBuf[c] = pack2(v.x, v.y);
    }
  };

  // ---- idx(0) + params ----
  if (t < 64) {
    sSrc[0][t] = (e00 + t < E) ? eidx[e00 + t] : 0;
  } else if (t < 128) {
    int r = t - 64, e = e00 + r;
    int d = (e < E) ? eidx[E + e] : 0;
    sDst[0][r] = d;
    if (use_sort && e < E) nxt[e] = atomicExch(&head[d], e);
  } else if (t < 256) {
    sG[t - 128] = gp[t - 128];
  } else if (t < 384) {
    sB[t - 256] = bep[t - 256];
  }
  __syncthreads();

  // ---- stage tile 0 ----
  if (nxbf) { gatherX(e00, sSrc[0], sDst[0]); writeX(); }
  else      stageXf32(e00, sSrc[0], sDst[0]);
  stageEA(e00);

  const float b0v = b0p[col], b1v = b1p[col], b2v = b2p[col];

#pragma unroll
  for (int tile = 0; tile < 2; ++tile) {
    const int e0 = e00 + tile * 64;
    __syncthreads();                       // staged tile visible
    if (tile == 0) {                       // idx(1) load (visible after next barrier)
      if (t < 64) {
        sSrc[1][t] = (e00 + 64 + t < E) ? eidx[e00 + 64 + t] : 0;
      } else if (t < 128) {
        int r = t - 64, e = e00 + 64 + r;
        int d = (e < E) ? eidx[E + e] : 0;
        sDst[1][r] = d;
        if (use_sort && e < E) nxt[e] = atomicExch(&head[d], e);
      }
    }

    f32x4 acc[4];
#pragma unroll
    for (int m = 0; m < 4; ++m) acc[m] = (f32x4){0.f, 0.f, 0.f, 0.f};

    // ---- layer 0: K=384, 4-deep pipelined B ----
#pragma unroll
    for (int ks = 0; ks < 12; ++ks) {
      bf16x8 bb = bx[ks & 3];
      if (ks + 4 < 12)
        bx[ks & 3] = *(const bf16x8*)(wp + (size_t)((w * 12 + ks + 4) * 64 + lane) * 8);
#pragma unroll
      for (int m = 0; m < 4; ++m) {
        bf16x8 a = *(const bf16x8*)&sBuf[(ks * 4 + m) * 512 + rdoff];
        acc[m] = __builtin_amdgcn_mfma_f32_16x16x32_bf16(a, bb, acc[m], 0, 0, 0);
      }
    }
    __syncthreads();                       // L0 A-reads done; idx(1) visible
    if (nxbf && tile == 0) gatherX(e00 + 64, sSrc[1], sDst[1]);   // async prefetch
#pragma unroll
    for (int k = 0; k < 4; ++k)            // bx -> B2r (L2 hits, hidden)
      bx[k] = *(const bf16x8*)(wp + 65536 + (size_t)((w * 4 + k) * 64 + lane) * 8);
    store_frag<true>(sBuf + stoff, acc, b0v);        // C0 -> chunks 0..1023
    __syncthreads();

    // ---- layer 1 ----
#pragma unroll
    for (int m = 0; m < 4; ++m) acc[m] = (f32x4){0.f, 0.f, 0.f, 0.f};
#pragma unroll
    for (int ks = 0; ks < 4; ++ks)
#pragma unroll
      for (int m = 0; m < 4; ++m) {
        bf16x8 a = *(const bf16x8*)&sBuf[(ks * 4 + m) * 512 + rdoff];
        acc[m] = __builtin_amdgcn_mfma_f32_16x16x32_bf16(a, B1r[ks], acc[m], 0, 0, 0);
      }
    store_frag<true>(sBuf + 8192 + stoff, acc, b1v); // C1 -> chunks 1024..2047
    __syncthreads();

    // ---- layer 2 (bx = B2r) ----
#pragma unroll
    for (int m = 0; m < 4; ++m) acc[m] = (f32x4){0.f, 0.f, 0.f, 0.f};
#pragma unroll
    for (int ks = 0; ks < 4; ++ks)
#pragma unroll
      for (int m = 0; m < 4; ++m) {
        bf16x8 a = *(const bf16x8*)&sBuf[8192 + (ks * 4 + m) * 512 + rdoff];
        acc[m] = __builtin_amdgcn_mfma_f32_16x16x32_bf16(a, bx[ks], acc[m], 0, 0, 0);
      }
    store_frag<false>(sBuf + stoff, acc, b2v);       // h2 -> chunks 0..1023
    __syncthreads();

    // ---- fused LN stats + epilogue ----
    {
      int row = t >> 3, j = t & 7;
      int a0 = (((j >> 1) * 4 + (row >> 4)) * 64 + (row & 15) * 4 + 2 * (j & 1)) * 8;
      bf16x8 v0 = *(const bf16x8*)&sBuf[a0];
      bf16x8 v1 = *(const bf16x8*)&sBuf[a0 + 8];
      float s1 = 0.f, s2 = 0.f;
#pragma unroll
      for (int q = 0; q < 8; ++q) {
        float a = (float)v0[q], b = (float)v1[q];
        s1 += a + b; s2 += a * a + b * b;
      }
#pragma unroll
      for (int m = 1; m < 8; m <<= 1) {
        s1 += __shfl_xor(s1, m, 64);
        s2 += __shfl_xor(s2, m, 64);
      }
      float mean = s1 * (1.f / 128.f);
      float var  = s2 * (1.f / 128.f) - mean * mean;
      float rstd = rsqrtf(fmaxf(var, 0.f) + 1e-5f);

      int e = e0 + row;
      if (e < E) {
        bf16x8 ea0 = *(const bf16x8*)&sBuf[a0 + 16384];
        bf16x8 ea1 = *(const bf16x8*)&sBuf[a0 + 16384 + 8];
        float val[16];
#pragma unroll
        for (int q = 0; q < 8; ++q) {
          val[q]     = ((float)v0[q] - mean) * rstd * sG[j * 16 + q]     + sB[j * 16 + q]     + (float)ea0[q];
          val[8 + q] = ((float)v1[q] - mean) * rstd * sG[j * 16 + 8 + q] + sB[j * 16 + 8 + q] + (float)ea1[q];
        }
        if (use_sort) {
          uint4* dst = (uint4*)(msg + (size_t)e * FD + j * 16);
          dst[0] = pack8(val);
          dst[1] = pack8(val + 8);
        } else {
          float* ap = agg + (size_t)sDst[tile][row] * FD + j * 16;
#pragma unroll
          for (int q = 0; q < 16; ++q) atomicAdd(ap + q, val[q]);
        }
      }
    }

    if (tile == 0) {
      __syncthreads();                     // tile0 LDS fully consumed
      if (nxbf) writeX();
      else      stageXf32(e00 + 64, sSrc[1], sDst[1]);
      stageEA(e00 + 64);
#pragma unroll
      for (int k = 0; k < 4; ++k)          // refill bx with L0 frags for tile1
        bx[k] = *(const bf16x8*)(wp + (size_t)((w * 12 + k) * 64 + lane) * 8);
    }
  }
}

// Node kernel: 64 nodes/block (R7 verbatim).
__global__ __launch_bounds__(512, 8)
void in_node_kernel(const float* __restrict__ node_x, const unsigned short* __restrict__ nxbf,
                    const unsigned short* __restrict__ msg, const int* __restrict__ head,
                    const int* __restrict__ nxt, const float* __restrict__ agg,
                    const unsigned short* __restrict__ wp,
                    const float* __restrict__ b0p, const float* __restrict__ b1p,
                    const float* __restrict__ b2p, const float* __restrict__ gp,
                    const float* __restrict__ bep, float* __restrict__ out,
                    int use_sort, int N) {
  __shared__ unsigned short sBuf[2048 * 8];   // 32KB frag-order buffer
  __shared__ float sG[128], sB[128];

  const int t = threadIdx.x;
  const int r0 = blockIdx.x * 64;
  const int lane = t & 63, w = t >> 6;
  const int ln = lane & 15, g16 = lane >> 4;
  const int col = w * 16 + ln;
  const int rdoff = ln * 32 + g16 * 8;
  const int stoff = (w >> 1) * 2048 + g16 * 128
                  + (((2 * w) + (ln >> 3)) & 3) * 8 + (ln & 7);

  bf16x8 b0[4];
#pragma unroll
  for (int ks = 0; ks < 4; ++ks)
    b0[ks] = *(const bf16x8*)(wp + 81920 + (size_t)((w * 8 + ks) * 64 + lane) * 8);

  if (t < 128)      sG[t] = gp[t];
  else if (t < 256) sB[t - 128] = bep[t - 128];

  if (nxbf) {
#pragma unroll
    for (int it = 0; it < 2; ++it) {
      int f = t + it * 512;
      int row = f >> 4, j = f & 15;
      int r = r0 + row;
      uint4 v = {0, 0, 0, 0};
      if (r < N) v = *(const uint4*)(nxbf + (size_t)r * FD + j * 8);
      int c = (((j >> 2) * 4 + (row >> 4)) * 64 + (row & 15) * 4 + (j & 3)) * 8;
      *(uint4*)&sBuf[c] = v;
    }
  } else {
#pragma unroll
    for (int it = 0; it < 8; ++it) {
      int row = (it << 3) + w;
      int r = r0 + row;
      float2 v = {0.f, 0.f};
      if (r < N) v = *(const float2*)(node_x + (size_t)r * FD + lane * 2);
      int c = (((lane >> 4) * 4 + (row >> 4)) * 64
               + (row & 15) * 4 + ((lane >> 2) & 3)) * 8 + (lane & 3) * 2;
      *(unsigned int*)&sBuf[c] = pack2(v.x, v.y);
    }
  }

  {
    int row = t >> 3, j = t & 7;
    int node = r0 + row;
    float a[16];
#pragma unroll
    for (int q = 0; q < 16; ++q) a[q] = 0.f;
    if (node < N) {
      if (use_sort) {
        int e = head[node];
        while (e >= 0) {
          int ne = nxt[e];
          bf16x8 m0 = *(const bf16x8*)(msg + (size_t)e * FD + j * 16);
          bf16x8 m1 = *(const bf16x8*)(msg + (size_t)e * FD + j * 16 + 8);
#pragma unroll
          for (int q = 0; q < 8; ++q) { a[q] += (float)m0[q]; a[8 + q] += (float)m1[q]; }
          e = ne;
        }
      } else {
        const float* ap = agg + (size_t)node * FD + j * 16;
#pragma unroll
        for (int q4 = 0; q4 < 4; ++q4) {
          f32x4 u = *(const f32x4*)(ap + q4 * 4);
#pragma unroll
          for (int q = 0; q < 4; ++q) a[q4 * 4 + q] = u[q];
        }
      }
    }
    int c = 8192 + (((j >> 1) * 4 + (row >> 4)) * 64 + (row & 15) * 4 + 2 * (j & 1)) * 8;
    *(uint4*)&sBuf[c] = pack8(a);
    *(uint4*)&sBuf[c + 8] = pack8(a + 8);
  }
  __syncthreads();

  const float b0v = b0p[col], b1v = b1p[col], b2v = b2p[col];

  f32x4 acc[4];
#pragma unroll
  for (int m = 0; m < 4; ++m) acc[m] = (f32x4){0.f, 0.f, 0.f, 0.f};

#pragma unroll
  for (int ks = 0; ks < 8; ++ks) {
    bf16x8 bb = b0[ks % 4];
    if (ks + 4 < 8)
      b0[ks % 4] = *(const bf16x8*)(wp + 81920 + (size_t)((w * 8 + ks + 4) * 64 + lane) * 8);
#pragma unroll
    for (int m = 0; m < 4; ++m) {
      bf16x8 a = *(const bf16x8*)&sBuf[(ks * 4 + m) * 512 + rdoff];
      acc[m] = __builtin_amdgcn_mfma_f32_16x16x32_bf16(a, bb, acc[m], 0, 0, 0);
    }
  }
  bf16x8 B1r[4];
#pragma unroll
  for (int ks = 0; ks < 4; ++ks)
    B1r[ks] = *(const bf16x8*)(wp + 114688 + (size_t)((w * 4 + ks) * 64 + lane) * 8);

  __syncthreads();
  store_frag<true>(sBuf + stoff, acc, b0v);
  __syncthreads();

#pragma unroll
  for (int m = 0; m < 4; ++m) acc[m] = (f32x4){0.f, 0.f, 0.f, 0.f};
#pragma unroll
  for (int ks = 0; ks < 4; ++ks)
#pragma unroll
    for (int m = 0; m < 4; ++m) {
      bf16x8 a = *(const bf16x8*)&sBuf[(ks * 4 + m) * 512 + rdoff];
      acc[m] = __builtin_amdgcn_mfma_f32_16x16x32_bf16(a, B1r[ks], acc[m], 0, 0, 0);
    }
  bf16x8 B2r[4];
#pragma unroll
  for (int ks = 0; ks < 4; ++ks)
    B2r[ks] = *(const bf16x8*)(wp + 131072 + (size_t)((w * 4 + ks) * 64 + lane) * 8);
  store_frag<true>(sBuf + 8192 + stoff, acc, b1v);
  __syncthreads();

#pragma unroll
  for (int m = 0; m < 4; ++m) acc[m] = (f32x4){0.f, 0.f, 0.f, 0.f};
#pragma unroll
  for (int ks = 0; ks < 4; ++ks)
#pragma unroll
    for (int m = 0; m < 4; ++m) {
      bf16x8 a = *(const bf16x8*)&sBuf[8192 + (ks * 4 + m) * 512 + rdoff];
      acc[m] = __builtin_amdgcn_mfma_f32_16x16x32_bf16(a, B2r[ks], acc[m], 0, 0, 0);
    }
  store_frag<false>(sBuf + stoff, acc, b2v);
  __syncthreads();

  {
    int row = t >> 3, j = t & 7;
    int a0 = (((j >> 1) * 4 + (row >> 4)) * 64 + (row & 15) * 4 + 2 * (j & 1)) * 8;
    bf16x8 v0 = *(const bf16x8*)&sBuf[a0];
    bf16x8 v1 = *(const bf16x8*)&sBuf[a0 + 8];
    float s1 = 0.f, s2 = 0.f;
#pragma unroll
    for (int q = 0; q < 8; ++q) {
      float a = (float)v0[q], b = (float)v1[q];
      s1 += a + b; s2 += a * a + b * b;
    }
#pragma unroll
    for (int m = 1; m < 8; m <<= 1) {
      s1 += __shfl_xor(s1, m, 64);
      s2 += __shfl_xor(s2, m, 64);
    }
    float mean = s1 * (1.f / 128.f);
    float var  = s2 * (1.f / 128.f) - mean * mean;
    float rstd = rsqrtf(fmaxf(var, 0.f) + 1e-5f);

    int node = r0 + row;
    if (node < N) {
      float o[16];
#pragma unroll
      for (int q = 0; q < 8; ++q) {
        o[q]     = ((float)v0[q] - mean) * rstd * sG[j * 16 + q]     + sB[j * 16 + q];
        o[8 + q] = ((float)v1[q] - mean) * rstd * sG[j * 16 + 8 + q] + sB[j * 16 + 8 + q];
      }
      const float* xr = node_x + (size_t)node * FD + j * 16;
      float* orow = out + (size_t)node * FD + j * 16;
#pragma unroll
      for (int q4 = 0; q4 < 4; ++q4) {
        f32x4 x = *(const f32x4*)(xr + q4 * 4);
        f32x4 wv;
#pragma unroll
        for (int q = 0; q < 4; ++q) wv[q] = o[q4 * 4 + q] + x[q];
        *(f32x4*)(orow + q4 * 4) = wv;
      }
    }
  }
}

extern "C" void kernel_launch(void* const* d_in, const int* in_sizes, int n_in,
                              void* d_out, int out_size, void* d_ws, size_t ws_size,
                              hipStream_t stream) {
  const float* node_x    = (const float*)d_in[0];
  const float* edge_attr = (const float*)d_in[1];
  const int*   eidx      = (const int*)d_in[2];
  const int N = in_sizes[0] / FD;
  const int E = in_sizes[1] / FD;

  char* ws = (char*)d_ws;
  auto aln = [](size_t x) { return (x + 255) & ~(size_t)255; };
  const size_t wpB   = aln(294912);
  const size_t nxbfB = aln((size_t)N * FD * 2);
  const size_t headB = aln((size_t)N * 4);
  const size_t nxtB  = aln((size_t)E * 4);
  const size_t msgB  = (size_t)E * FD * 2;

  unsigned short* wp = (unsigned short*)ws;
  unsigned short* nxbf = nullptr;
  int* head = nullptr; int* nxt = nullptr;
  unsigned short* msg = nullptr; float* agg = nullptr;
  int use_sort = 0;

  if (ws_size >= wpB + nxbfB + headB + nxtB + msgB) {          // full: bf16 table + sort
    use_sort = 1;
    nxbf = (unsigned short*)(ws + wpB);
    head = (int*)(ws + wpB + nxbfB);
    nxt  = (int*)(ws + wpB + nxbfB + headB);
    msg  = (unsigned short*)(ws + wpB + nxbfB + headB + nxtB);
  } else if (ws_size >= wpB + headB + nxtB + msgB) {           // sort, no bf16 table
    use_sort = 1;
    head = (int*)(ws + wpB);
    nxt  = (int*)(ws + wpB + headB);
    msg  = (unsigned short*)(ws + wpB + headB + nxtB);
  } else {                                                     // atomic fallback
    agg = (float*)(ws + wpB);
  }

  if (use_sort) (void)hipMemsetAsync(head, 0xFF, (size_t)N * 4, stream);
  else          (void)hipMemsetAsync(agg, 0, (size_t)N * FD * sizeof(float), stream);

  pack_weights<<<576, 256, 0, stream>>>(
      (const float*)d_in[3], (const float*)d_in[5], (const float*)d_in[7],
      (const float*)d_in[11], (const float*)d_in[13], (const float*)d_in[15], wp);
  if (nxbf) cvt_bf16<<<(N * FD / 8 + 255) / 256, 256, 0, stream>>>(node_x, nxbf, N * FD / 8);
  in_edge_kernel<<<(E + 127) / 128, 512, 0, stream>>>(
      node_x, nxbf, edge_attr, eidx, wp,
      (const float*)d_in[4], (const float*)d_in[6], (const float*)d_in[8],
      (const float*)d_in[9], (const float*)d_in[10],
      msg, head, nxt, agg, use_sort, E);
  in_node_kernel<<<(N + 63) / 64, 512, 0, stream>>>(
      node_x, nxbf, msg, head, nxt, agg, wp,
      (const float*)d_in[12], (const float*)d_in[14], (const float*)d_in[16],
      (const float*)d_in[17], (const float*)d_in[18], (float*)d_out, use_sort, N);
}

// Round 10
// 245.001 us; speedup vs baseline: 1.6289x; 1.6289x over previous
//
#include <hip/hip_runtime.h>

typedef __attribute__((ext_vector_type(4))) float f32x4;
typedef __attribute__((ext_vector_type(8))) __bf16 bf16x8;

constexpr int FD = 128;   // feature dim D = H = 128

__device__ __forceinline__ uint4 pack8(const float* v) {
  union { __bf16 h[8]; uint4 u; } cv;
#pragma unroll
  for (int q = 0; q < 8; ++q) cv.h[q] = (__bf16)v[q];
  return cv.u;
}
__device__ __forceinline__ unsigned int pack2(float a, float b) {
  union { __bf16 h[2]; unsigned int u; } cv;
  cv.h[0] = (__bf16)a; cv.h[1] = (__bf16)b;
  return cv.u;
}

// node_x f32 -> bf16 table (halves random-gather bytes in the edge kernel)
__global__ void cvt_bf16(const float* __restrict__ x, unsigned short* __restrict__ o, int n8) {
  int i = blockIdx.x * 256 + threadIdx.x;
  if (i >= n8) return;
  const float* p = x + (size_t)i * 8;
  float v[8];
#pragma unroll
  for (int q = 0; q < 8; ++q) v[q] = p[q];
  *(uint4*)(o + (size_t)i * 8) = pack8(v);
}

// Pack a (K,128) f32 weight matrix into 16x16x32 MFMA B-fragment order, bf16:
// dst[((nt*KS + ks)*64 + lane)*8 + e] = W[k][n]
__global__ void pack_weights(const float* __restrict__ mw0, const float* __restrict__ mw1,
                             const float* __restrict__ mw2, const float* __restrict__ uw0,
                             const float* __restrict__ uw1, const float* __restrict__ uw2,
                             unsigned short* __restrict__ wp) {
  int tid = blockIdx.x * 256 + threadIdx.x;   // 576*256 == 147456 exactly
  const float* src; int base, K;
  if      (tid < 49152)  { src = mw0; base = 0;      K = 384; }
  else if (tid < 65536)  { src = mw1; base = 49152;  K = 128; }
  else if (tid < 81920)  { src = mw2; base = 65536;  K = 128; }
  else if (tid < 114688) { src = uw0; base = 81920;  K = 256; }
  else if (tid < 131072) { src = uw1; base = 114688; K = 128; }
  else                   { src = uw2; base = 131072; K = 128; }
  int i = tid - base;
  int k = i >> 7, n = i & 127;
  int KS = K >> 5;
  int dst = base + (((n >> 4) * KS + (k >> 5)) * 64 + ((k >> 3) & 3) * 16 + (n & 15)) * 8 + (k & 7);
  union { __bf16 h; unsigned short s; } cv; cv.h = (__bf16)src[i];
  wp[dst] = cv.s;
}

// Fragment-order LDS layout (R7, validated): chunk(ks,mm) at shorts offset
// ((ks*4+mm)*64)*8; per-lane read offset rdoff = (ln*4+g16)*8.

// Edge kernel: 64 edges/block, 512 threads = 8 waves arranged 2 row-groups x
// 4 col-groups (wave = 32 rows x 32 cols). Halves LDS A-read traffic vs the
// 8-col-group layout: each row-chunk read by 4 waves instead of 8.
__global__ __launch_bounds__(512, 6)
void in_edge_kernel(const float* __restrict__ node_x, const unsigned short* __restrict__ nxbf,
                    const float* __restrict__ edge_attr,
                    const int* __restrict__ eidx, const unsigned short* __restrict__ wp,
                    const float* __restrict__ b0p, const float* __restrict__ b1p,
                    const float* __restrict__ b2p, const float* __restrict__ gp,
                    const float* __restrict__ bep,
                    unsigned short* __restrict__ msg, int* __restrict__ head,
                    int* __restrict__ nxt, float* __restrict__ agg,
                    int use_sort, int E) {
  __shared__ unsigned short sBuf[3072 * 8];   // 48KB frag-order buffer
  __shared__ int sSrc[64], sDst[64];
  __shared__ float sG[128], sB[128];

  const int t = threadIdx.x;
  const int e0 = blockIdx.x * 64;
  const int lane = t & 63, w = t >> 6;
  const int ln = lane & 15, g16 = lane >> 4;
  const int rg = w & 1;                       // row-group: rows rg*32..+31
  const int cg = w >> 1;                      // col-group: cols cg*32..+31
  const int nt0 = cg * 2, nt1 = cg * 2 + 1;   // the wave's two 16-col B blocks
  const int rdoff = ln * 32 + g16 * 8;
  // store offset (R7 formula with wblk = cg*2+nj): base + perm(nj) + mm*512 + ri*32
  const int stf = cg * 2048 + g16 * 128 + (ln & 7);
  const int perm0 = (((ln >> 3)) & 3) * 8;            // nj = 0
  const int perm1 = ((2 + (ln >> 3)) & 3) * 8;        // nj = 1

  // B pool: 8 frags (2 nt x 4-deep), reused across L0-stream/B1/B2 phases.
  bf16x8 BA[8];
#pragma unroll
  for (int k = 0; k < 4; ++k) {
    BA[k]     = *(const bf16x8*)(wp + (size_t)((nt0 * 12 + k) * 64 + lane) * 8);
    BA[4 + k] = *(const bf16x8*)(wp + (size_t)((nt1 * 12 + k) * 64 + lane) * 8);
  }

  if (t < 64) {
    sSrc[t] = (e0 + t < E) ? eidx[e0 + t] : 0;
  } else if (t < 128) {
    int r = t - 64;
    int e = e0 + r;
    int d = (e < E) ? eidx[E + e] : 0;
    sDst[r] = d;
    if (use_sort && e < E) nxt[e] = atomicExch(&head[d], e);   // linked-list build
  } else if (t < 256) {
    sG[t - 128] = gp[t - 128];
  } else if (t < 384) {
    sB[t - 256] = bep[t - 256];
  }
  __syncthreads();

  // ---- stage concat tile into frag order (R7 verbatim) ----
  if (nxbf) {
#pragma unroll
    for (int it = 0; it < 2; ++it) {
      int f = t + it * 512;
      int row = f >> 4, j = f & 15;
      uint4 v = {0, 0, 0, 0}, u = {0, 0, 0, 0};
      if (e0 + row < E) {
        v = *(const uint4*)(nxbf + (size_t)sDst[row] * FD + j * 8);
        u = *(const uint4*)(nxbf + (size_t)sSrc[row] * FD + j * 8);
      }
      int c = (((j >> 2) * 4 + (row >> 4)) * 64 + (row & 15) * 4 + (j & 3)) * 8;
      *(uint4*)&sBuf[c] = v;                 // x_dst: ks 0..3
      *(uint4*)&sBuf[c + 8192] = u;          // x_src: ks 4..7
    }
  } else {
#pragma unroll
    for (int it = 0; it < 16; ++it) {
      const int type = it >> 3;
      int row = ((it & 7) << 3) + w;
      float2 v = {0.f, 0.f};
      if (e0 + row < E) {
        const float* sp = (type == 0) ? node_x + (size_t)sDst[row] * FD
                                      : node_x + (size_t)sSrc[row] * FD;
        v = *(const float2*)(sp + lane * 2);
      }
      int c = (((type * 4 + (lane >> 4)) * 4 + (row >> 4)) * 64
               + (row & 15) * 4 + ((lane >> 2) & 3)) * 8 + (lane & 3) * 2;
      *(unsigned int*)&sBuf[c] = pack2(v.x, v.y);
    }
  }
#pragma unroll
  for (int it = 0; it < 8; ++it) {           // edge_attr -> ks 8..11
    int row = it * 8 + w;
    float2 v = {0.f, 0.f};
    if (e0 + row < E) v = *(const float2*)(edge_attr + (size_t)(e0 + row) * FD + lane * 2);
    int c = 16384 + (((lane >> 4) * 4 + (row >> 4)) * 64
                     + (row & 15) * 4 + ((lane >> 2) & 3)) * 8 + (lane & 3) * 2;
    *(unsigned int*)&sBuf[c] = pack2(v.x, v.y);
  }
  __syncthreads();

  const float b0A = b0p[cg * 32 + ln],      b0B = b0p[cg * 32 + 16 + ln];
  const float b1A = b1p[cg * 32 + ln],      b1B = b1p[cg * 32 + 16 + ln];
  const float b2A = b2p[cg * 32 + ln],      b2B = b2p[cg * 32 + 16 + ln];

  f32x4 acc[2][2];
#pragma unroll
  for (int mi = 0; mi < 2; ++mi)
#pragma unroll
    for (int nj = 0; nj < 2; ++nj) acc[mi][nj] = (f32x4){0.f, 0.f, 0.f, 0.f};

  // ---- layer 0: K=384, dual-nt 4-deep pipelined B ----
#pragma unroll
  for (int ks = 0; ks < 12; ++ks) {
    bf16x8 bbA = BA[ks & 3];
    bf16x8 bbB = BA[4 + (ks & 3)];
    if (ks + 4 < 12) {
      BA[ks & 3]       = *(const bf16x8*)(wp + (size_t)((nt0 * 12 + ks + 4) * 64 + lane) * 8);
      BA[4 + (ks & 3)] = *(const bf16x8*)(wp + (size_t)((nt1 * 12 + ks + 4) * 64 + lane) * 8);
    }
#pragma unroll
    for (int mi = 0; mi < 2; ++mi) {
      bf16x8 a = *(const bf16x8*)&sBuf[(ks * 4 + rg * 2 + mi) * 512 + rdoff];
      acc[mi][0] = __builtin_amdgcn_mfma_f32_16x16x32_bf16(a, bbA, acc[mi][0], 0, 0, 0);
      acc[mi][1] = __builtin_amdgcn_mfma_f32_16x16x32_bf16(a, bbB, acc[mi][1], 0, 0, 0);
    }
  }
  // reload BA <- B1 (hidden under barrier + C0 store)
#pragma unroll
  for (int k = 0; k < 4; ++k) {
    BA[k]     = *(const bf16x8*)(wp + 49152 + (size_t)((nt0 * 4 + k) * 64 + lane) * 8);
    BA[4 + k] = *(const bf16x8*)(wp + 49152 + (size_t)((nt1 * 4 + k) * 64 + lane) * 8);
  }
  __syncthreads();                            // all L0 A-reads done

  // C0 = relu(h0+b0) -> chunks 0..1023
#pragma unroll
  for (int mi = 0; mi < 2; ++mi)
#pragma unroll
    for (int ri = 0; ri < 4; ++ri) {
      union { __bf16 h; unsigned short s; } c0, c1;
      c0.h = (__bf16)fmaxf(acc[mi][0][ri] + b0A, 0.f);
      c1.h = (__bf16)fmaxf(acc[mi][1][ri] + b0B, 0.f);
      int o = (rg * 2 + mi) * 512 + ri * 32 + stf;
      sBuf[o + perm0] = c0.s;
      sBuf[o + perm1] = c1.s;
      acc[mi][0][ri] = 0.f; acc[mi][1][ri] = 0.f;
    }
  __syncthreads();

  // ---- layer 1: K=128 ----
#pragma unroll
  for (int ks = 0; ks < 4; ++ks)
#pragma unroll
    for (int mi = 0; mi < 2; ++mi) {
      bf16x8 a = *(const bf16x8*)&sBuf[(ks * 4 + rg * 2 + mi) * 512 + rdoff];
      acc[mi][0] = __builtin_amdgcn_mfma_f32_16x16x32_bf16(a, BA[ks], acc[mi][0], 0, 0, 0);
      acc[mi][1] = __builtin_amdgcn_mfma_f32_16x16x32_bf16(a, BA[4 + ks], acc[mi][1], 0, 0, 0);
    }
  // reload BA <- B2
#pragma unroll
  for (int k = 0; k < 4; ++k) {
    BA[k]     = *(const bf16x8*)(wp + 65536 + (size_t)((nt0 * 4 + k) * 64 + lane) * 8);
    BA[4 + k] = *(const bf16x8*)(wp + 65536 + (size_t)((nt1 * 4 + k) * 64 + lane) * 8);
  }
  // C1 -> chunks 1024..2047 (x_src dead)
#pragma unroll
  for (int mi = 0; mi < 2; ++mi)
#pragma unroll
    for (int ri = 0; ri < 4; ++ri) {
      union { __bf16 h; unsigned short s; } c0, c1;
      c0.h = (__bf16)fmaxf(acc[mi][0][ri] + b1A, 0.f);
      c1.h = (__bf16)fmaxf(acc[mi][1][ri] + b1B, 0.f);
      int o = 8192 + (rg * 2 + mi) * 512 + ri * 32 + stf;
      sBuf[o + perm0] = c0.s;
      sBuf[o + perm1] = c1.s;
      acc[mi][0][ri] = 0.f; acc[mi][1][ri] = 0.f;
    }
  __syncthreads();

  // ---- layer 2: K=128 ----
#pragma unroll
  for (int ks = 0; ks < 4; ++ks)
#pragma unroll
    for (int mi = 0; mi < 2; ++mi) {
      bf16x8 a = *(const bf16x8*)&sBuf[8192 + (ks * 4 + rg * 2 + mi) * 512 + rdoff];
      acc[mi][0] = __builtin_amdgcn_mfma_f32_16x16x32_bf16(a, BA[ks], acc[mi][0], 0, 0, 0);
      acc[mi][1] = __builtin_amdgcn_mfma_f32_16x16x32_bf16(a, BA[4 + ks], acc[mi][1], 0, 0, 0);
    }
  // h2 -> chunks 0..1023 (C0 dead)
#pragma unroll
  for (int mi = 0; mi < 2; ++mi)
#pragma unroll
    for (int ri = 0; ri < 4; ++ri) {
      union { __bf16 h; unsigned short s; } c0, c1;
      c0.h = (__bf16)(acc[mi][0][ri] + b2A);
      c1.h = (__bf16)(acc[mi][1][ri] + b2B);
      int o = (rg * 2 + mi) * 512 + ri * 32 + stf;
      sBuf[o + perm0] = c0.s;
      sBuf[o + perm1] = c1.s;
    }
  __syncthreads();

  // ---- fused LN stats + epilogue, row-wise (R7 verbatim) ----
  {
    int row = t >> 3, j = t & 7;
    int a0 = (((j >> 1) * 4 + (row >> 4)) * 64 + (row & 15) * 4 + 2 * (j & 1)) * 8;
    bf16x8 v0 = *(const bf16x8*)&sBuf[a0];
    bf16x8 v1 = *(const bf16x8*)&sBuf[a0 + 8];
    float s1 = 0.f, s2 = 0.f;
#pragma unroll
    for (int q = 0; q < 8; ++q) {
      float a = (float)v0[q], b = (float)v1[q];
      s1 += a + b; s2 += a * a + b * b;
    }
#pragma unroll
    for (int m = 1; m < 8; m <<= 1) {
      s1 += __shfl_xor(s1, m, 64);
      s2 += __shfl_xor(s2, m, 64);
    }
    float mean = s1 * (1.f / 128.f);
    float var  = s2 * (1.f / 128.f) - mean * mean;
    float rstd = rsqrtf(fmaxf(var, 0.f) + 1e-5f);

    int e = e0 + row;
    if (e < E) {
      bf16x8 ea0 = *(const bf16x8*)&sBuf[a0 + 16384];
      bf16x8 ea1 = *(const bf16x8*)&sBuf[a0 + 16384 + 8];
      float val[16];
#pragma unroll
      for (int q = 0; q < 8; ++q) {
        val[q]     = ((float)v0[q] - mean) * rstd * sG[j * 16 + q]     + sB[j * 16 + q]     + (float)ea0[q];
        val[8 + q] = ((float)v1[q] - mean) * rstd * sG[j * 16 + 8 + q] + sB[j * 16 + 8 + q] + (float)ea1[q];
      }
      if (use_sort) {
        uint4* dst = (uint4*)(msg + (size_t)e * FD + j * 16);
        dst[0] = pack8(val);
        dst[1] = pack8(val + 8);
      } else {
        float* ap = agg + (size_t)sDst[row] * FD + j * 16;
#pragma unroll
        for (int q = 0; q < 16; ++q) atomicAdd(ap + q, val[q]);
      }
    }
  }
}

// Node kernel: 64 nodes/block (R7 verbatim).
__global__ __launch_bounds__(512, 8)
void in_node_kernel(const float* __restrict__ node_x, const unsigned short* __restrict__ nxbf,
                    const unsigned short* __restrict__ msg, const int* __restrict__ head,
                    const int* __restrict__ nxt, const float* __restrict__ agg,
                    const unsigned short* __restrict__ wp,
                    const float* __restrict__ b0p, const float* __restrict__ b1p,
                    const float* __restrict__ b2p, const float* __restrict__ gp,
                    const float* __restrict__ bep, float* __restrict__ out,
                    int use_sort, int N) {
  __shared__ unsigned short sBuf[2048 * 8];   // 32KB frag-order buffer
  __shared__ float sG[128], sB[128];

  const int t = threadIdx.x;
  const int r0 = blockIdx.x * 64;
  const int lane = t & 63, w = t >> 6;
  const int ln = lane & 15, g16 = lane >> 4;
  const int col = w * 16 + ln;
  const int rdoff = ln * 32 + g16 * 8;
  const int stoff = (w >> 1) * 2048 + g16 * 128
                  + (((2 * w) + (ln >> 3)) & 3) * 8 + (ln & 7);

  bf16x8 b0[4];
#pragma unroll
  for (int ks = 0; ks < 4; ++ks)
    b0[ks] = *(const bf16x8*)(wp + 81920 + (size_t)((w * 8 + ks) * 64 + lane) * 8);

  if (t < 128)      sG[t] = gp[t];
  else if (t < 256) sB[t - 128] = bep[t - 128];

  if (nxbf) {
#pragma unroll
    for (int it = 0; it < 2; ++it) {
      int f = t + it * 512;
      int row = f >> 4, j = f & 15;
      int r = r0 + row;
      uint4 v = {0, 0, 0, 0};
      if (r < N) v = *(const uint4*)(nxbf + (size_t)r * FD + j * 8);
      int c = (((j >> 2) * 4 + (row >> 4)) * 64 + (row & 15) * 4 + (j & 3)) * 8;
      *(uint4*)&sBuf[c] = v;
    }
  } else {
#pragma unroll
    for (int it = 0; it < 8; ++it) {
      int row = (it << 3) + w;
      int r = r0 + row;
      float2 v = {0.f, 0.f};
      if (r < N) v = *(const float2*)(node_x + (size_t)r * FD + lane * 2);
      int c = (((lane >> 4) * 4 + (row >> 4)) * 64
               + (row & 15) * 4 + ((lane >> 2) & 3)) * 8 + (lane & 3) * 2;
      *(unsigned int*)&sBuf[c] = pack2(v.x, v.y);
    }
  }

  {
    int row = t >> 3, j = t & 7;
    int node = r0 + row;
    float a[16];
#pragma unroll
    for (int q = 0; q < 16; ++q) a[q] = 0.f;
    if (node < N) {
      if (use_sort) {
        int e = head[node];
        while (e >= 0) {
          int ne = nxt[e];
          bf16x8 m0 = *(const bf16x8*)(msg + (size_t)e * FD + j * 16);
          bf16x8 m1 = *(const bf16x8*)(msg + (size_t)e * FD + j * 16 + 8);
#pragma unroll
          for (int q = 0; q < 8; ++q) { a[q] += (float)m0[q]; a[8 + q] += (float)m1[q]; }
          e = ne;
        }
      } else {
        const float* ap = agg + (size_t)node * FD + j * 16;
#pragma unroll
        for (int q4 = 0; q4 < 4; ++q4) {
          f32x4 u = *(const f32x4*)(ap + q4 * 4);
#pragma unroll
          for (int q = 0; q < 4; ++q) a[q4 * 4 + q] = u[q];
        }
      }
    }
    int c = 8192 + (((j >> 1) * 4 + (row >> 4)) * 64 + (row & 15) * 4 + 2 * (j & 1)) * 8;
    *(uint4*)&sBuf[c] = pack8(a);
    *(uint4*)&sBuf[c + 8] = pack8(a + 8);
  }
  __syncthreads();

  const float b0v = b0p[col], b1v = b1p[col], b2v = b2p[col];

  f32x4 acc[4];
#pragma unroll
  for (int m = 0; m < 4; ++m) acc[m] = (f32x4){0.f, 0.f, 0.f, 0.f};

#pragma unroll
  for (int ks = 0; ks < 8; ++ks) {
    bf16x8 bb = b0[ks % 4];
    if (ks + 4 < 8)
      b0[ks % 4] = *(const bf16x8*)(wp + 81920 + (size_t)((w * 8 + ks + 4) * 64 + lane) * 8);
#pragma unroll
    for (int m = 0; m < 4; ++m) {
      bf16x8 a = *(const bf16x8*)&sBuf[(ks * 4 + m) * 512 + rdoff];
      acc[m] = __builtin_amdgcn_mfma_f32_16x16x32_bf16(a, bb, acc[m], 0, 0, 0);
    }
  }
  bf16x8 B1r[4];
#pragma unroll
  for (int ks = 0; ks < 4; ++ks)
    B1r[ks] = *(const bf16x8*)(wp + 114688 + (size_t)((w * 4 + ks) * 64 + lane) * 8);

  __syncthreads();
#pragma unroll
  for (int m = 0; m < 4; ++m)
#pragma unroll
    for (int ri = 0; ri < 4; ++ri) {
      union { __bf16 h; unsigned short s; } cv;
      cv.h = (__bf16)fmaxf(acc[m][ri] + b0v, 0.f);
      sBuf[stoff + m * 512 + ri * 32] = cv.s;
      acc[m][ri] = 0.f;
    }
  __syncthreads();

#pragma unroll
  for (int ks = 0; ks < 4; ++ks)
#pragma unroll
    for (int m = 0; m < 4; ++m) {
      bf16x8 a = *(const bf16x8*)&sBuf[(ks * 4 + m) * 512 + rdoff];
      acc[m] = __builtin_amdgcn_mfma_f32_16x16x32_bf16(a, B1r[ks], acc[m], 0, 0, 0);
    }
  bf16x8 B2r[4];
#pragma unroll
  for (int ks = 0; ks < 4; ++ks)
    B2r[ks] = *(const bf16x8*)(wp + 131072 + (size_t)((w * 4 + ks) * 64 + lane) * 8);
#pragma unroll
  for (int m = 0; m < 4; ++m)
#pragma unroll
    for (int ri = 0; ri < 4; ++ri) {
      union { __bf16 h; unsigned short s; } cv;
      cv.h = (__bf16)fmaxf(acc[m][ri] + b1v, 0.f);
      sBuf[8192 + stoff + m * 512 + ri * 32] = cv.s;
      acc[m][ri] = 0.f;
    }
  __syncthreads();

#pragma unroll
  for (int ks = 0; ks < 4; ++ks)
#pragma unroll
    for (int m = 0; m < 4; ++m) {
      bf16x8 a = *(const bf16x8*)&sBuf[8192 + (ks * 4 + m) * 512 + rdoff];
      acc[m] = __builtin_amdgcn_mfma_f32_16x16x32_bf16(a, B2r[ks], acc[m], 0, 0, 0);
    }
#pragma unroll
  for (int m = 0; m < 4; ++m)
#pragma unroll
    for (int ri = 0; ri < 4; ++ri) {
      union { __bf16 h; unsigned short s; } cv;
      cv.h = (__bf16)(acc[m][ri] + b2v);
      sBuf[stoff + m * 512 + ri * 32] = cv.s;
    }
  __syncthreads();

  {
    int row = t >> 3, j = t & 7;
    int a0 = (((j >> 1) * 4 + (row >> 4)) * 64 + (row & 15) * 4 + 2 * (j & 1)) * 8;
    bf16x8 v0 = *(const bf16x8*)&sBuf[a0];
    bf16x8 v1 = *(const bf16x8*)&sBuf[a0 + 8];
    float s1 = 0.f, s2 = 0.f;
#pragma unroll
    for (int q = 0; q < 8; ++q) {
      float a = (float)v0[q], b = (float)v1[q];
      s1 += a + b; s2 += a * a + b * b;
    }
#pragma unroll
    for (int m = 1; m < 8; m <<= 1) {
      s1 += __shfl_xor(s1, m, 64);
      s2 += __shfl_xor(s2, m, 64);
    }
    float mean = s1 * (1.f / 128.f);
    float var  = s2 * (1.f / 128.f) - mean * mean;
    float rstd = rsqrtf(fmaxf(var, 0.f) + 1e-5f);

    int node = r0 + row;
    if (node < N) {
      float o[16];
#pragma unroll
      for (int q = 0; q < 8; ++q) {
        o[q]     = ((float)v0[q] - mean) * rstd * sG[j * 16 + q]     + sB[j * 16 + q];
        o[8 + q] = ((float)v1[q] - mean) * rstd * sG[j * 16 + 8 + q] + sB[j * 16 + 8 + q];
      }
      const float* xr = node_x + (size_t)node * FD + j * 16;
      float* orow = out + (size_t)node * FD + j * 16;
#pragma unroll
      for (int q4 = 0; q4 < 4; ++q4) {
        f32x4 x = *(const f32x4*)(xr + q4 * 4);
        f32x4 wv;
#pragma unroll
        for (int q = 0; q < 4; ++q) wv[q] = o[q4 * 4 + q] + x[q];
        *(f32x4*)(orow + q4 * 4) = wv;
      }
    }
  }
}

extern "C" void kernel_launch(void* const* d_in, const int* in_sizes, int n_in,
                              void* d_out, int out_size, void* d_ws, size_t ws_size,
                              hipStream_t stream) {
  const float* node_x    = (const float*)d_in[0];
  const float* edge_attr = (const float*)d_in[1];
  const int*   eidx      = (const int*)d_in[2];
  const int N = in_sizes[0] / FD;
  const int E = in_sizes[1] / FD;

  char* ws = (char*)d_ws;
  auto aln = [](size_t x) { return (x + 255) & ~(size_t)255; };
  const size_t wpB   = aln(294912);
  const size_t nxbfB = aln((size_t)N * FD * 2);
  const size_t headB = aln((size_t)N * 4);
  const size_t nxtB  = aln((size_t)E * 4);
  const size_t msgB  = (size_t)E * FD * 2;

  unsigned short* wp = (unsigned short*)ws;
  unsigned short* nxbf = nullptr;
  int* head = nullptr; int* nxt = nullptr;
  unsigned short* msg = nullptr; float* agg = nullptr;
  int use_sort = 0;

  if (ws_size >= wpB + nxbfB + headB + nxtB + msgB) {          // full: bf16 table + sort
    use_sort = 1;
    nxbf = (unsigned short*)(ws + wpB);
    head = (int*)(ws + wpB + nxbfB);
    nxt  = (int*)(ws + wpB + nxbfB + headB);
    msg  = (unsigned short*)(ws + wpB + nxbfB + headB + nxtB);
  } else if (ws_size >= wpB + headB + nxtB + msgB) {           // sort, no bf16 table
    use_sort = 1;
    head = (int*)(ws + wpB);
    nxt  = (int*)(ws + wpB + headB);
    msg  = (unsigned short*)(ws + wpB + headB + nxtB);
  } else {                                                     // atomic fallback
    agg = (float*)(ws + wpB);
  }

  if (use_sort) (void)hipMemsetAsync(head, 0xFF, (size_t)N * 4, stream);
  else          (void)hipMemsetAsync(agg, 0, (size_t)N * FD * sizeof(float), stream);

  pack_weights<<<576, 256, 0, stream>>>(
      (const float*)d_in[3], (const float*)d_in[5], (const float*)d_in[7],
      (const float*)d_in[11], (const float*)d_in[13], (const float*)d_in[15], wp);
  if (nxbf) cvt_bf16<<<(N * FD / 8 + 255) / 256, 256, 0, stream>>>(node_x, nxbf, N * FD / 8);
  in_edge_kernel<<<(E + 63) / 64, 512, 0, stream>>>(
      node_x, nxbf, edge_attr, eidx, wp,
      (const float*)d_in[4], (const float*)d_in[6], (const float*)d_in[8],
      (const float*)d_in[9], (const float*)d_in[10],
      msg, head, nxt, agg, use_sort, E);
  in_node_kernel<<<(N + 63) / 64, 512, 0, stream>>>(
      node_x, nxbf, msg, head, nxt, agg, wp,
      (const float*)d_in[12], (const float*)d_in[14], (const float*)d_in[16],
      (const float*)d_in[17], (const float*)d_in[18], (float*)d_out, use_sort, N);
}